// Round 17
// baseline (99.558 us; speedup 1.0000x reference)
//
#include <hip/hip_runtime.h>
#include <math.h>

// Problem constants
#define NH 16
#define DM 1024
#define FEAT 384          // 2*64*3
#define SB 4096           // S*B
#define SEQ 2048

static constexpr float SCALE = 0.125f;  // 1/sqrt(64)
static constexpr float EPS = 1e-5f;

typedef __attribute__((ext_vector_type(8))) _Float16 half8;
typedef __attribute__((ext_vector_type(4))) _Float16 half4;
typedef __attribute__((ext_vector_type(4))) float f32x4;

#define AS1 __attribute__((address_space(1)))
#define AS3 __attribute__((address_space(3)))

// swizzled 16B-cell index into a [rows][64-half] LDS tile (row = 128B = 8 cells)
#define IDX(r, o) ((((r) << 6)) + ((((o) ^ ((r) & 7))) << 3))

// ---------------------------------------------------------------------------
// prep: h -> hF (MFMA-fragment-ordered f16) + weight transposes.
// hF layout: hF[((rt*16+kt)*32 + g*2 + ks)*512 + l*8 .. +8] =
//   h[rt*256 + g*16 + (l&15)][kt*64 + ks*32 + (l>>4)*8 .. +8]
// so gemm A-fragment loads are fully coalesced 16B/lane.
// grid 4352: [0,256) hF; [256,3328) Wqkv transpose; [3328,4352) Wo.
// ---------------------------------------------------------------------------
__global__ __launch_bounds__(256) void prep_kernel(const float* __restrict__ h,
                                                   const float* __restrict__ Wq,
                                                   const float* __restrict__ Wkv,
                                                   const float* __restrict__ Wo,
                                                   _Float16* __restrict__ hF,
                                                   _Float16* __restrict__ WqkvT,
                                                   _Float16* __restrict__ WoT) {
    __shared__ _Float16 tile[32][33];
    int bid = blockIdx.x, t = threadIdx.x;
    if (bid < 256) {
        int rt = bid >> 4, kt = bid & 15;
        #pragma unroll
        for (int i = 0; i < 8; ++i) {
            int tt = t + 256 * i;      // 0..2047
            int g = tt >> 7;           // 0..15 (16-row group)
            int ks = (tt >> 6) & 1;
            int ll = tt & 63;
            int row = rt * 256 + g * 16 + (ll & 15);
            int col = kt * 64 + ks * 32 + (ll >> 4) * 8;
            const float4 s0 = *(const float4*)&h[(size_t)row * 1024 + col];
            const float4 s1 = *(const float4*)&h[(size_t)row * 1024 + col + 4];
            half8 o = {(_Float16)s0.x, (_Float16)s0.y, (_Float16)s0.z, (_Float16)s0.w,
                       (_Float16)s1.x, (_Float16)s1.y, (_Float16)s1.z, (_Float16)s1.w};
            *(half8*)&hF[((size_t)(rt * 16 + kt) * 32 + g * 2 + ks) * 512 + ll * 8] = o;
        }
        return;
    }
    const float* src;
    _Float16* dst;
    int N, col0, n0, k0;
    if (bid < 3328) {
        int b2 = bid - 256;
        n0 = (b2 % 96) * 32; k0 = (b2 / 96) * 32;
        if (n0 < 1024) { src = Wq; N = 1024; col0 = n0; }
        else           { src = Wkv; N = 2048; col0 = n0 - 1024; }
        dst = WqkvT;
    } else {
        int b3 = bid - 3328;
        n0 = (b3 & 31) * 32; k0 = (b3 >> 5) * 32;
        src = Wo; N = 1024; col0 = n0; dst = WoT;
    }
    int tx = t & 31, ty = t >> 5;
    #pragma unroll
    for (int i = 0; i < 4; ++i)
        tile[ty + i * 8][tx] = (_Float16)src[(size_t)(k0 + ty + i * 8) * N + col0 + tx];
    __syncthreads();
    #pragma unroll
    for (int i = 0; i < 4; ++i)
        dst[(size_t)(n0 + ty + i * 8) * 1024 + k0 + tx] = tile[tx][ty + i * 8];
}

// ---------------------------------------------------------------------------
// qkv GEMM v6 ("A-in-regs"): 256x192 tile, BK=64, 512 threads = 8 waves
// (4M x 2N), wave tile 64x96. A-fragments loaded global->reg (coalesced via
// hF fragment layout, reg-double-buffered, loop unrolled x2); B via LDS
// (2 buf x 192x64 = 48 KB, XOR-swizzled). Single barrier per K-tile.
// LDS read traffic 96 KB/tile (vs 160 with A in LDS) -> LDS-BW bound lifted.
// ---------------------------------------------------------------------------
__global__ __launch_bounds__(512) void gemm_qkv(const _Float16* __restrict__ AF,
                                                const _Float16* __restrict__ BT,
                                                _Float16* __restrict__ C,
                                                int M, int N, int K) {
    __shared__ _Float16 smem[2 * 12288];   // 48 KB
    const int t = threadIdx.x;
    const int w = t >> 6, l = t & 63;
    const int wr = w >> 1, wc = w & 1;
    const int NT = K >> 6;   // 16 (even)

    int nwg = gridDim.x;
    int cpx = nwg >> 3;
    int bid = blockIdx.x;
    int swz = (bid & 7) * cpx + (bid >> 3);
    int ntile = N / 192;
    int rt = swz / ntile;            // 0..15
    int row0 = rt << 8;
    int col0 = (swz % ntile) * 192;

    f32x4 acc[4][6];
    #pragma unroll
    for (int m = 0; m < 4; ++m)
        #pragma unroll
        for (int n = 0; n < 6; ++n)
            acc[m][n] = (f32x4){0.f, 0.f, 0.f, 0.f};

    const int lr = l >> 3;
    const int lc8 = ((l & 7) ^ lr) * 8;

    // B stage (3 loads/thread) into buf[tau&1]
    auto STAGE_B = [&](int tau) {
        if (tau >= NT) return;
        int kk = tau << 6;
        int bufo = (tau & 1) * 12288;
        #pragma unroll
        for (int i = 0; i < 2; ++i) {
            int chunk = w * 2 + i;   // rows 0..127
            const _Float16* src = BT + (size_t)(col0 + chunk * 8 + lr) * K + kk + lc8;
            __builtin_amdgcn_global_load_lds((const AS1 void*)src,
                (AS3 void*)(smem + bufo + chunk * 512), 16, 0, 0);
        }
        {
            const _Float16* src = BT + (size_t)(col0 + 128 + w * 8 + lr) * K + kk + lc8;
            __builtin_amdgcn_global_load_lds((const AS1 void*)src,
                (AS3 void*)(smem + bufo + 8192 + w * 512), 16, 0, 0);
        }
    };

    // A fragment loads: global->reg, coalesced (hF fragment order)
    const _Float16* afb = AF + (size_t)rt * 16 * 32 * 512;
    auto LOADA = [&](int tau, half8 (&ar)[4][2]) {
        if (tau >= NT) return;
        const _Float16* ap = afb + ((size_t)tau * 32 + wr * 8) * 512 + l * 8;
        #pragma unroll
        for (int mf = 0; mf < 4; ++mf)
            #pragma unroll
            for (int ks = 0; ks < 2; ++ks)
                ar[mf][ks] = *(const half8*)&ap[(size_t)(mf * 2 + ks) * 512];
    };

    auto LDB = [&](int bufo, half8 (&bv)[6][2]) {
        #pragma unroll
        for (int nf = 0; nf < 6; ++nf) {
            int r = wc * 96 + nf * 16 + (l & 15);
            #pragma unroll
            for (int ks = 0; ks < 2; ++ks) {
                int c16 = (ks * 4 + (l >> 4)) ^ (r & 7);
                bv[nf][ks] = *(const half8*)&smem[bufo + r * 64 + c16 * 8];
            }
        }
    };

    half8 aA[4][2], aB[4][2], bv[6][2];

    LOADA(0, aA);
    STAGE_B(0);
    asm volatile("s_waitcnt vmcnt(0)" ::: "memory");
    __builtin_amdgcn_s_barrier();

    #pragma unroll 1
    for (int ti = 0; ti < NT; ti += 2) {
        // ---- even tile ti: compute with aA; prefetch ti+1 (aB + B-stage)
        LOADA(ti + 1, aB);
        STAGE_B(ti + 1);
        LDB((ti & 1) * 12288, bv);
        __builtin_amdgcn_sched_barrier(0);
        asm volatile("s_waitcnt lgkmcnt(0)" ::: "memory");
        __builtin_amdgcn_sched_barrier(0);
        __builtin_amdgcn_s_setprio(1);
        #pragma unroll
        for (int mf = 0; mf < 4; ++mf)
            #pragma unroll
            for (int nf = 0; nf < 6; ++nf)
                #pragma unroll
                for (int ks = 0; ks < 2; ++ks)
                    acc[mf][nf] = __builtin_amdgcn_mfma_f32_16x16x32_f16(
                        aA[mf][ks], bv[nf][ks], acc[mf][nf], 0, 0, 0);
        __builtin_amdgcn_s_setprio(0);
        __builtin_amdgcn_sched_barrier(0);
        asm volatile("s_waitcnt vmcnt(0)" ::: "memory");
        __builtin_amdgcn_s_barrier();
        // ---- odd tile ti+1: compute with aB; prefetch ti+2 (aA + B-stage)
        LOADA(ti + 2, aA);
        STAGE_B(ti + 2);
        LDB(((ti + 1) & 1) * 12288, bv);
        __builtin_amdgcn_sched_barrier(0);
        asm volatile("s_waitcnt lgkmcnt(0)" ::: "memory");
        __builtin_amdgcn_sched_barrier(0);
        __builtin_amdgcn_s_setprio(1);
        #pragma unroll
        for (int mf = 0; mf < 4; ++mf)
            #pragma unroll
            for (int nf = 0; nf < 6; ++nf)
                #pragma unroll
                for (int ks = 0; ks < 2; ++ks)
                    acc[mf][nf] = __builtin_amdgcn_mfma_f32_16x16x32_f16(
                        aB[mf][ks], bv[nf][ks], acc[mf][nf], 0, 0, 0);
        __builtin_amdgcn_s_setprio(0);
        __builtin_amdgcn_sched_barrier(0);
        asm volatile("s_waitcnt vmcnt(0)" ::: "memory");
        __builtin_amdgcn_s_barrier();
    }

    int ocol = l & 15, orow4 = (l >> 4) * 4;
    #pragma unroll
    for (int mf = 0; mf < 4; ++mf)
        #pragma unroll
        for (int nf = 0; nf < 6; ++nf) {
            size_t base = (size_t)(row0 + wr * 64 + mf * 16 + orow4) * N
                        + col0 + wc * 96 + nf * 16 + ocol;
            #pragma unroll
            for (int j = 0; j < 4; ++j)
                C[base + (size_t)j * N] = (_Float16)acc[mf][nf][j];
        }
}

// ---------------------------------------------------------------------------
// gemm_wo: 128x128 tile, BK=64, 4 waves (2x2), 3-buffer LDS (96 KB),
// single phase per K-tile, counted vmcnt(8). (Wo projection only)
// ---------------------------------------------------------------------------
__global__ __launch_bounds__(256) void gemm_wo(const _Float16* __restrict__ A,
                                               const _Float16* __restrict__ BT,
                                               _Float16* __restrict__ C,
                                               int M, int N, int K) {
    __shared__ _Float16 smem[3 * 16384];
    const int t = threadIdx.x;
    const int w = t >> 6, l = t & 63;
    const int wr = w >> 1, wc = w & 1;
    const int NT = K >> 6;
    int row0 = blockIdx.y * 128, col0 = blockIdx.x * 128;

    f32x4 acc[4][4];
    #pragma unroll
    for (int m = 0; m < 4; ++m)
        #pragma unroll
        for (int n = 0; n < 4; ++n)
            acc[m][n] = (f32x4){0.f, 0.f, 0.f, 0.f};

    const int lr = l >> 3;
    const int lc8 = ((l & 7) ^ lr) * 8;

    auto STAGE = [&](int ti) {
        if (ti >= NT) return;
        int kk = ti << 6;
        int bufo = (ti % 3) * 16384;
        #pragma unroll
        for (int i = 0; i < 4; ++i) {
            int chunk = w * 4 + i;
            const _Float16* asrc = A + (size_t)(row0 + chunk * 8 + lr) * K + kk + lc8;
            __builtin_amdgcn_global_load_lds((const AS1 void*)asrc,
                (AS3 void*)(smem + bufo + chunk * 512), 16, 0, 0);
            const _Float16* bsrc = BT + (size_t)(col0 + chunk * 8 + lr) * K + kk + lc8;
            __builtin_amdgcn_global_load_lds((const AS1 void*)bsrc,
                (AS3 void*)(smem + bufo + 8192 + chunk * 512), 16, 0, 0);
        }
    };

    STAGE(0); STAGE(1);
    asm volatile("s_waitcnt vmcnt(8)" ::: "memory");
    __builtin_amdgcn_s_barrier();

    #pragma unroll 1
    for (int ti = 0; ti < NT; ++ti) {
        const int bufo = (ti % 3) * 16384;
        half8 a[4][2], bv[4][2];
        #pragma unroll
        for (int mf = 0; mf < 4; ++mf) {
            int r = wr * 64 + mf * 16 + (l & 15);
            #pragma unroll
            for (int ks = 0; ks < 2; ++ks) {
                int c16 = (ks * 4 + (l >> 4)) ^ (r & 7);
                a[mf][ks] = *(const half8*)&smem[bufo + r * 64 + c16 * 8];
            }
        }
        #pragma unroll
        for (int nf = 0; nf < 4; ++nf) {
            int r = wc * 64 + nf * 16 + (l & 15);
            #pragma unroll
            for (int ks = 0; ks < 2; ++ks) {
                int c16 = (ks * 4 + (l >> 4)) ^ (r & 7);
                bv[nf][ks] = *(const half8*)&smem[bufo + 8192 + r * 64 + c16 * 8];
            }
        }
        STAGE(ti + 2);
        __builtin_amdgcn_sched_barrier(0);
        asm volatile("s_waitcnt lgkmcnt(0)" ::: "memory");
        __builtin_amdgcn_sched_barrier(0);
        __builtin_amdgcn_s_setprio(1);
        #pragma unroll
        for (int mf = 0; mf < 4; ++mf)
            #pragma unroll
            for (int nf = 0; nf < 4; ++nf)
                #pragma unroll
                for (int ks = 0; ks < 2; ++ks)
                    acc[mf][nf] = __builtin_amdgcn_mfma_f32_16x16x32_f16(
                        a[mf][ks], bv[nf][ks], acc[mf][nf], 0, 0, 0);
        __builtin_amdgcn_s_setprio(0);
        __builtin_amdgcn_sched_barrier(0);
        if (ti < NT - 2) asm volatile("s_waitcnt vmcnt(8)" ::: "memory");
        else             asm volatile("s_waitcnt vmcnt(0)" ::: "memory");
        __builtin_amdgcn_s_barrier();
    }

    int ocol = l & 15, orow = (l >> 4) * 4;
    #pragma unroll
    for (int mf = 0; mf < 4; ++mf)
        #pragma unroll
        for (int nf = 0; nf < 4; ++nf) {
            size_t base = (size_t)(row0 + wr * 64 + mf * 16 + orow) * N
                        + col0 + wc * 64 + nf * 16 + ocol;
            #pragma unroll
            for (int j = 0; j < 4; ++j)
                C[base + (size_t)j * N] = (_Float16)acc[mf][nf][j];
        }
}

// ---------------------------------------------------------------------------
// kvagg_fused: per (bn, jseg): on-the-fly DPFP(k) + v, MFMA accumulate.
// jseg = 8 segments of 256 j's, grid (32, 8). f16 partials.
// ---------------------------------------------------------------------------
__global__ __launch_bounds__(512) void kvagg_fused(const _Float16* __restrict__ qkv,
                                                   _Float16* __restrict__ kvp,
                                                   float* __restrict__ zp) {
    __shared__ _Float16 x2s[128 * 64];    // 16 KB
    __shared__ _Float16 vTs[64 * 64];     //  8 KB
    __shared__ _Float16 pkTs[384 * 64];   // 48 KB
    const int t = threadIdx.x;
    const int w = t >> 6, l = t & 63;
    const int bn = blockIdx.x;
    const int jseg = blockIdx.y;    // 0..7 (256 j's each)
    const int b = bn >> 4, nh = bn & 15;

    f32x4 acc[4][3];
    #pragma unroll
    for (int mf = 0; mf < 4; ++mf)
        #pragma unroll
        for (int nf = 0; nf < 3; ++nf)
            acc[mf][nf] = (f32x4){0.f, 0.f, 0.f, 0.f};
    float zacc[3] = {0.f, 0.f, 0.f};

    const int sc = t & 63;
    const int so = t >> 6;

    #pragma unroll 1
    for (int ch = 0; ch < 4; ++ch) {
        int j0 = jseg * 256 + ch * 64;
        _Float16 kx[8], vx[8];
        #pragma unroll
        for (int e = 0; e < 8; ++e) {
            size_t rb = (size_t)((j0 + so * 8 + e) * 2 + b) * 3072 + nh * 64 + sc;
            kx[e] = qkv[rb + 1024];
            vx[e] = qkv[rb + 2048];
        }
        half8 xlo, xhi, vv;
        #pragma unroll
        for (int e = 0; e < 8; ++e) {
            float kf = (float)kx[e];
            xlo[e] = (_Float16)fmaxf(kf, 0.f);
            xhi[e] = (_Float16)fmaxf(-kf, 0.f);
            vv[e] = vx[e];
        }
        if (ch) __syncthreads();
        *(half8*)&x2s[IDX(sc, so)] = xlo;
        *(half8*)&x2s[IDX(sc + 64, so)] = xhi;
        *(half8*)&vTs[IDX(sc, so)] = vv;
        __syncthreads();
        {
            const int o = t & 7;
            const int fb = t >> 3;
            #pragma unroll
            for (int it = 0; it < 6; ++it) {
                int f = it * 64 + fb;
                int fm = f & 127;
                int r = (f >> 7) + 1;
                int fm2 = (fm - r) & 127;
                half8 pa = *(const half8*)&x2s[IDX(fm, o)];
                half8 pb = *(const half8*)&x2s[IDX(fm2, o)];
                *(half8*)&pkTs[IDX(f, o)] = pa * pb;
            }
        }
        __syncthreads();
        #pragma unroll
        for (int ks = 0; ks < 2; ++ks) {
            half8 a[4], bq[3];
            int oo = ks * 4 + (l >> 4);
            #pragma unroll
            for (int mf = 0; mf < 4; ++mf) {
                int dr = mf * 16 + (l & 15);
                a[mf] = *(const half8*)&vTs[IDX(dr, oo)];
            }
            #pragma unroll
            for (int nf = 0; nf < 3; ++nf) {
                int fr = w * 48 + nf * 16 + (l & 15);
                bq[nf] = *(const half8*)&pkTs[IDX(fr, oo)];
                #pragma unroll
                for (int e = 0; e < 8; ++e) zacc[nf] += (float)bq[nf][e];
            }
            #pragma unroll
            for (int mf = 0; mf < 4; ++mf)
                #pragma unroll
                for (int nf = 0; nf < 3; ++nf)
                    acc[mf][nf] = __builtin_amdgcn_mfma_f32_16x16x32_f16(
                        a[mf], bq[nf], acc[mf][nf], 0, 0, 0);
        }
    }

    #pragma unroll
    for (int nf = 0; nf < 3; ++nf) {
        float v = zacc[nf];
        v += __shfl_xor(v, 16, 64);
        v += __shfl_xor(v, 32, 64);
        if (l < 16)
            zp[(size_t)(jseg * 32 + bn) * FEAT + w * 48 + nf * 16 + l] = v;
    }
    _Float16* outp = kvp + (size_t)(jseg * 32 + bn) * 64 * FEAT;
    int orow = (l >> 4) * 4, ocol = l & 15;
    #pragma unroll
    for (int mf = 0; mf < 4; ++mf)
        #pragma unroll
        for (int nf = 0; nf < 3; ++nf) {
            int fcol = w * 48 + nf * 16 + ocol;
            #pragma unroll
            for (int j = 0; j < 4; ++j)
                outp[(size_t)(mf * 16 + orow + j) * FEAT + fcol] = (_Float16)acc[mf][nf][j];
        }
}

// ---------------------------------------------------------------------------
// Reduce 8 j-segments (f16 partials) -> kvaggT f16 [32][64][384], z f32
// ---------------------------------------------------------------------------
__global__ __launch_bounds__(256) void reduceA(const _Float16* __restrict__ kvp,
                                               const float* __restrict__ zp,
                                               _Float16* __restrict__ kvaggT,
                                               float* __restrict__ z) {
    const int NKV = 32 * 64 * FEAT;  // 786432
    int idx = blockIdx.x * 256 + threadIdx.x;
    if (idx < NKV) {
        float s = 0.f;
        #pragma unroll
        for (int c = 0; c < 8; ++c) s += (float)kvp[(size_t)c * NKV + idx];
        kvaggT[idx] = (_Float16)s;
    } else if (idx < NKV + 32 * FEAT) {
        int e = idx - NKV;
        float s = 0.f;
        #pragma unroll
        for (int c = 0; c < 8; ++c) s += zp[c * 32 * FEAT + e];
        z[e] = s;
    }
}

// ---------------------------------------------------------------------------
// attn_fused v2: 64 rows x 64 d per block, grid (32, 32), 256 threads.
// pq in registers via rotated-row trick. z reads vectorized.
// ---------------------------------------------------------------------------
#define X2STR 152   // 128 + 24 right-extension (max csel=24), halves
__global__ __launch_bounds__(256) void attn_fused(const _Float16* __restrict__ qkv,
                                                  const _Float16* __restrict__ kvaggT,
                                                  const float* __restrict__ z,
                                                  _Float16* __restrict__ av) {
    __shared__ _Float16 x2e[64 * X2STR];   // 19,456 B
    __shared__ _Float16 B_lds[64 * FEAT];  // 49,152 B, 16B-cell swizzle
    __shared__ float z_lds[FEAT];
    __shared__ float den_lds[64];
    const int t = threadIdx.x;
    const int w = t >> 6, l = t & 63;
    const int iblk = blockIdx.x;
    const int bn = blockIdx.y;
    const int b = bn >> 4, nh = bn & 15;

    {
        const _Float16* Bg = kvaggT + (size_t)bn * 64 * FEAT;
        #pragma unroll
        for (int s = 0; s < 12; ++s) {
            int idx8 = t + 256 * s;
            int row = idx8 / 48, c16 = idx8 - row * 48;
            half8 vv = *(const half8*)&Bg[row * FEAT + c16 * 8];
            *(half8*)&B_lds[row * FEAT + ((c16 ^ (row & 7)) << 3)] = vv;
        }
    }
    for (int e = t; e < FEAT; e += 256) z_lds[e] = z[(size_t)bn * FEAT + e];

    {
        int row = t >> 2, c0 = (t & 3) * 16;
        const _Float16* qrow = qkv + (size_t)((iblk * 64 + row) * 2 + b) * 3072 + nh * 64;
        half8 q0 = *(const half8*)&qrow[c0];
        half8 q1 = *(const half8*)&qrow[c0 + 8];
        half8 lo0, lo1, hi0, hi1;
        #pragma unroll
        for (int e = 0; e < 8; ++e) {
            float f0 = (float)q0[e], f1 = (float)q1[e];
            lo0[e] = (_Float16)fmaxf(f0, 0.f);
            lo1[e] = (_Float16)fmaxf(f1, 0.f);
            hi0[e] = (_Float16)fmaxf(-f0, 0.f);
            hi1[e] = (_Float16)fmaxf(-f1, 0.f);
        }
        _Float16* xr = &x2e[row * X2STR];
        *(half8*)&xr[c0] = lo0;
        *(half8*)&xr[c0 + 8] = lo1;
        *(half8*)&xr[64 + c0] = hi0;
        *(half8*)&xr[64 + c0 + 8] = hi1;
        if (c0 == 0) { *(half8*)&xr[128] = lo0; *(half8*)&xr[136] = lo1; }
        if (c0 == 16) { *(half8*)&xr[144] = lo0; }
    }
    __syncthreads();

    const int rloc16 = l & 15;
    const int csel = (l >> 4) * 8;
    const int lrow = w * 16 + rloc16;
    half8 y8[16];
    {
        const _Float16* xr = &x2e[lrow * X2STR + csel];
        #pragma unroll
        for (int j = 0; j < 16; ++j)
            y8[j] = *(const half8*)&xr[j * 8];
    }
    half8 afr[12];
    #pragma unroll
    for (int ks = 0; ks < 12; ++ks) {
        const int r = (ks >> 2) + 1;
        #pragma unroll
        for (int e = 0; e < 8; ++e) {
            const int j1 = ((ks & 3) * 32 + e) & 127;
            const int j2 = ((ks & 3) * 32 + e - r) & 127;
            afr[ks][e] = y8[j1 >> 3][j1 & 7] * y8[j2 >> 3][j2 & 7];
        }
    }

    f32x4 acc[4];
    #pragma unroll
    for (int n = 0; n < 4; ++n) acc[n] = (f32x4){0.f, 0.f, 0.f, 0.f};
    float den = 0.f;
    #pragma unroll
    for (int ks = 0; ks < 12; ++ks) {
        const float4 z0 = *(const float4*)&z_lds[ks * 32 + csel];
        const float4 z1 = *(const float4*)&z_lds[ks * 32 + csel + 4];
        den += (float)afr[ks][0] * z0.x + (float)afr[ks][1] * z0.y
             + (float)afr[ks][2] * z0.z + (float)afr[ks][3] * z0.w
             + (float)afr[ks][4] * z1.x + (float)afr[ks][5] * z1.y
             + (float)afr[ks][6] * z1.z + (float)afr[ks][7] * z1.w;
        #pragma unroll
        for (int nf = 0; nf < 4; ++nf) {
            int row = nf * 16 + rloc16;
            int c16 = (ks * 4 + (l >> 4)) ^ (row & 7);
            half8 bfr = *(const half8*)&B_lds[row * FEAT + (c16 << 3)];
            acc[nf] = __builtin_amdgcn_mfma_f32_16x16x32_f16(afr[ks], bfr, acc[nf], 0, 0, 0);
        }
    }

    den += __shfl_xor(den, 16, 64);
    den += __shfl_xor(den, 32, 64);
    if (l < 16) den_lds[w * 16 + l] = den;
    __syncthreads();

    #pragma unroll
    for (int nf = 0; nf < 4; ++nf)
        #pragma unroll
        for (int j = 0; j < 4; ++j) {
            int rl = w * 16 + (l >> 4) * 4 + j;
            float dv = den_lds[rl] * SCALE + EPS;
            float val = acc[nf][j] * SCALE / dv;
            int i = iblk * 64 + rl;
            av[((size_t)i * 2 + b) * 1024 + nh * 64 + nf * 16 + (l & 15)] = (_Float16)val;
        }
}

// ---------------------------------------------------------------------------
// Residual + LayerNorm, vectorized (float4 / half4).
// ---------------------------------------------------------------------------
__global__ __launch_bounds__(256) void ln_kernel(const float* __restrict__ h,
                                                 const _Float16* __restrict__ attn_out,
                                                 const float* __restrict__ gamma,
                                                 const float* __restrict__ beta,
                                                 float* __restrict__ out) {
    int r = blockIdx.x;
    int t = threadIdx.x;
    const float4 hv = ((const float4*)(h + (size_t)r * 1024))[t];
    const half4 a4 = ((const half4*)(attn_out + (size_t)r * 1024))[t];
    float x[4] = {hv.x + (float)a4[0], hv.y + (float)a4[1],
                  hv.z + (float)a4[2], hv.w + (float)a4[3]};
    float sum = x[0] + x[1] + x[2] + x[3];
    float sq = x[0]*x[0] + x[1]*x[1] + x[2]*x[2] + x[3]*x[3];
    #pragma unroll
    for (int off = 32; off >= 1; off >>= 1) {
        sum += __shfl_xor(sum, off, 64);
        sq += __shfl_xor(sq, off, 64);
    }
    __shared__ float ssum[4], ssq[4];
    int wl = t >> 6, lane = t & 63;
    if (lane == 0) { ssum[wl] = sum; ssq[wl] = sq; }
    __syncthreads();
    sum = ssum[0] + ssum[1] + ssum[2] + ssum[3];
    sq = ssq[0] + ssq[1] + ssq[2] + ssq[3];
    float mu = sum * (1.f / 1024.f);
    float var = sq * (1.f / 1024.f) - mu * mu;
    float rs = rsqrtf(var + 1e-5f);
    const float4 g4 = ((const float4*)gamma)[t];
    const float4 b4 = ((const float4*)beta)[t];
    float4 o;
    o.x = (x[0] - mu) * rs * g4.x + b4.x;
    o.y = (x[1] - mu) * rs * g4.y + b4.y;
    o.z = (x[2] - mu) * rs * g4.z + b4.z;
    o.w = (x[3] - mu) * rs * g4.w + b4.w;
    ((float4*)(out + (size_t)r * 1024))[t] = o;
}

// ---------------------------------------------------------------------------
extern "C" void kernel_launch(void* const* d_in, const int* in_sizes, int n_in,
                              void* d_out, int out_size, void* d_ws, size_t ws_size,
                              hipStream_t stream) {
    const float* h     = (const float*)d_in[0];
    const float* Wq    = (const float*)d_in[1];
    const float* Wkv   = (const float*)d_in[2];
    const float* Wo    = (const float*)d_in[3];
    const float* gamma = (const float*)d_in[4];
    const float* beta  = (const float*)d_in[5];
    float* out = (float*)d_out;
    _Float16* u = (_Float16*)d_ws;

    // Workspace (2-byte units)
    _Float16* hF     = u;                       // 8 MB fragment-ordered A; later av
    _Float16* WqkvT  = u + 4194304;             // 6 MB
    _Float16* WoT    = u + 7340032;             // 2 MB
    _Float16* qkv    = u + 8388608;             // 24 MB; later attn_out f16
    _Float16* kvp    = u + 20971520;            // f16 partials, 8 segs = 12.6 MB
    float*    zp     = (float*)(u + 33554432);  // 8x32x384 f32
    _Float16* kvaggT = u + 33751040;            // 1.5 MB
    float*    z      = (float*)(u + 34537472);  // 48 KB
    _Float16* av         = hF;
    _Float16* attn_out_h = qkv;

    dim3 blk(256);
    // 0) prep: h -> hF (fragment order) + weight transposes
    prep_kernel<<<dim3(4352), blk, 0, stream>>>(h, Wq, Wkv, Wo, hF, WqkvT, WoT);
    // 1) fused qkv projection (A-in-regs v6), grid 256 (%8==0)
    gemm_qkv<<<dim3(256), dim3(512), 0, stream>>>(hF, WqkvT, qkv, SB, 3072, DM);
    // 2) fused DPFP(k)+kvagg+z partials over (32 bn x 8 jseg)
    kvagg_fused<<<dim3(32, 8), dim3(512), 0, stream>>>(qkv, kvp, zp);
    // 3) reduce partials (8 segments)
    reduceA<<<dim3(3120), blk, 0, stream>>>(kvp, zp, kvaggT, z);
    // 4) fused featq + attn GEMM, pq-in-registers (grid 32 iblk x 32 bn)
    attn_fused<<<dim3(32, 32), blk, 0, stream>>>(qkv, kvaggT, z, av);
    // 5) output projection: 3-buffer counted-vmcnt kernel, grid (8, 32)
    gemm_wo<<<dim3(8, 32), blk, 0, stream>>>(av, WoT, attn_out_h, SB, 1024, DM);
    // 6) residual + LayerNorm
    ln_kernel<<<dim3(SB), blk, 0, stream>>>(h, attn_out_h, gamma, beta, out);
}

// Round 18
// 97.708 us; speedup vs baseline: 1.0189x; 1.0189x over previous
//
#include <hip/hip_runtime.h>
#include <math.h>

// Problem constants
#define NH 16
#define DM 1024
#define FEAT 384          // 2*64*3
#define SB 4096           // S*B
#define SEQ 2048

static constexpr float SCALE = 0.125f;  // 1/sqrt(64)
static constexpr float EPS = 1e-5f;

typedef __attribute__((ext_vector_type(8))) _Float16 half8;
typedef __attribute__((ext_vector_type(4))) _Float16 half4;
typedef __attribute__((ext_vector_type(4))) float f32x4;

#define AS1 __attribute__((address_space(1)))
#define AS3 __attribute__((address_space(3)))

// swizzled 16B-cell index into a [rows][64-half] LDS tile (row = 128B = 8 cells)
#define IDX(r, o) ((((r) << 6)) + ((((o) ^ ((r) & 7))) << 3))

// ---------------------------------------------------------------------------
// prep: merged f32->f16 conversion of h + weight transposes.
// ---------------------------------------------------------------------------
__global__ __launch_bounds__(256) void prep_kernel(const float* __restrict__ h,
                                                   const float* __restrict__ Wq,
                                                   const float* __restrict__ Wkv,
                                                   const float* __restrict__ Wo,
                                                   _Float16* __restrict__ h_h,
                                                   _Float16* __restrict__ WqkvT,
                                                   _Float16* __restrict__ WoT) {
    __shared__ _Float16 tile[32][33];
    int bid = blockIdx.x, t = threadIdx.x;
    if (bid < 4096) {
        int i = bid * 256 + t;
        const float4 v = ((const float4*)h)[i];
        half4 o = {(_Float16)v.x, (_Float16)v.y, (_Float16)v.z, (_Float16)v.w};
        ((half4*)h_h)[i] = o;
        return;
    }
    const float* src;
    _Float16* dst;
    int N, col0, n0, k0;
    if (bid < 7168) {
        int b2 = bid - 4096;
        n0 = (b2 % 96) * 32; k0 = (b2 / 96) * 32;
        if (n0 < 1024) { src = Wq; N = 1024; col0 = n0; }
        else           { src = Wkv; N = 2048; col0 = n0 - 1024; }
        dst = WqkvT;
    } else {
        int b3 = bid - 7168;
        n0 = (b3 & 31) * 32; k0 = (b3 >> 5) * 32;
        src = Wo; N = 1024; col0 = n0; dst = WoT;
    }
    int tx = t & 31, ty = t >> 5;
    #pragma unroll
    for (int i = 0; i < 4; ++i)
        tile[ty + i * 8][tx] = (_Float16)src[(size_t)(k0 + ty + i * 8) * N + col0 + tx];
    __syncthreads();
    #pragma unroll
    for (int i = 0; i < 4; ++i)
        dst[(size_t)(n0 + ty + i * 8) * 1024 + k0 + tx] = tile[tx][ty + i * 8];
}

// ---------------------------------------------------------------------------
// qkv GEMM v4 (best measured): 256x192 tile, BK=64, 512 threads = 8 waves
// (4M x 2N), wave tile 64x96. Single barrier per K-tile, depth-1 prefetch,
// 2-buffer LDS (112 KB). Grid 256 (%8==0), XCD swizzle.
// ---------------------------------------------------------------------------
__global__ __launch_bounds__(512) void gemm_qkv(const _Float16* __restrict__ A,
                                                const _Float16* __restrict__ BT,
                                                _Float16* __restrict__ C,
                                                int M, int N, int K) {
    __shared__ _Float16 smem[57344];   // 2 x 28672 halfs = 112 KiB
    const int t = threadIdx.x;
    const int w = t >> 6, l = t & 63;
    const int wr = w >> 1, wc = w & 1;
    const int NT = K >> 6;

    int nwg = gridDim.x;
    int cpx = nwg >> 3;
    int bid = blockIdx.x;
    int swz = (bid & 7) * cpx + (bid >> 3);
    int ntile = N / 192;
    int row0 = (swz / ntile) << 8;
    int col0 = (swz % ntile) * 192;

    f32x4 acc[4][6];
    #pragma unroll
    for (int m = 0; m < 4; ++m)
        #pragma unroll
        for (int n = 0; n < 6; ++n)
            acc[m][n] = (f32x4){0.f, 0.f, 0.f, 0.f};

    const int lr = l >> 3;
    const int lc8 = ((l & 7) ^ lr) * 8;

    auto STAGE_TILE = [&](int tau) {
        if (tau >= NT) return;
        int kk = tau << 6;
        int bufo = (tau & 1) * 28672;
        #pragma unroll
        for (int i = 0; i < 2; ++i) {
            int chunk = w * 2 + i;
            const _Float16* src = BT + (size_t)(col0 + chunk * 8 + lr) * K + kk + lc8;
            __builtin_amdgcn_global_load_lds((const AS1 void*)src,
                (AS3 void*)(smem + bufo + 16384 + chunk * 512), 16, 0, 0);
        }
        {
            const _Float16* src = BT + (size_t)(col0 + 128 + w * 8 + lr) * K + kk + lc8;
            __builtin_amdgcn_global_load_lds((const AS1 void*)src,
                (AS3 void*)(smem + bufo + 24576 + w * 512), 16, 0, 0);
        }
        #pragma unroll
        for (int i = 0; i < 4; ++i) {
            int chunk = w * 4 + i;   // 0..31, 8 rows each
            const _Float16* src = A + (size_t)(row0 + chunk * 8 + lr) * K + kk + lc8;
            __builtin_amdgcn_global_load_lds((const AS1 void*)src,
                (AS3 void*)(smem + bufo + chunk * 512), 16, 0, 0);
        }
    };

    STAGE_TILE(0);
    asm volatile("s_waitcnt vmcnt(0)" ::: "memory");
    __builtin_amdgcn_s_barrier();

    #pragma unroll 1
    for (int ti = 0; ti < NT; ++ti) {
        const int bufo = (ti & 1) * 28672;
        STAGE_TILE(ti + 1);
        half8 a[4][2], bv[6][2];
        #pragma unroll
        for (int mf = 0; mf < 4; ++mf) {
            int r = wr * 64 + mf * 16 + (l & 15);
            #pragma unroll
            for (int ks = 0; ks < 2; ++ks) {
                int c16 = (ks * 4 + (l >> 4)) ^ (r & 7);
                a[mf][ks] = *(const half8*)&smem[bufo + r * 64 + c16 * 8];
            }
        }
        #pragma unroll
        for (int nf = 0; nf < 6; ++nf) {
            int r = wc * 96 + nf * 16 + (l & 15);
            #pragma unroll
            for (int ks = 0; ks < 2; ++ks) {
                int c16 = (ks * 4 + (l >> 4)) ^ (r & 7);
                bv[nf][ks] = *(const half8*)&smem[bufo + 16384 + r * 64 + c16 * 8];
            }
        }
        __builtin_amdgcn_sched_barrier(0);
        asm volatile("s_waitcnt lgkmcnt(0)" ::: "memory");
        __builtin_amdgcn_sched_barrier(0);
        __builtin_amdgcn_s_setprio(1);
        #pragma unroll
        for (int mf = 0; mf < 4; ++mf)
            #pragma unroll
            for (int nf = 0; nf < 6; ++nf)
                #pragma unroll
                for (int ks = 0; ks < 2; ++ks)
                    acc[mf][nf] = __builtin_amdgcn_mfma_f32_16x16x32_f16(
                        a[mf][ks], bv[nf][ks], acc[mf][nf], 0, 0, 0);
        __builtin_amdgcn_s_setprio(0);
        __builtin_amdgcn_sched_barrier(0);
        asm volatile("s_waitcnt vmcnt(0)" ::: "memory");
        __builtin_amdgcn_s_barrier();
    }

    int ocol = l & 15, orow4 = (l >> 4) * 4;
    #pragma unroll
    for (int mf = 0; mf < 4; ++mf)
        #pragma unroll
        for (int nf = 0; nf < 6; ++nf) {
            size_t base = (size_t)(row0 + wr * 64 + mf * 16 + orow4) * N
                        + col0 + wc * 96 + nf * 16 + ocol;
            #pragma unroll
            for (int j = 0; j < 4; ++j)
                C[base + (size_t)j * N] = (_Float16)acc[mf][nf][j];
        }
}

// ---------------------------------------------------------------------------
// gemm_wo: 128x128 tile, BK=64, 4 waves (2x2), 3-buffer LDS (96 KB),
// single phase per K-tile, counted vmcnt(8). (Wo projection only)
// ---------------------------------------------------------------------------
__global__ __launch_bounds__(256) void gemm_wo(const _Float16* __restrict__ A,
                                               const _Float16* __restrict__ BT,
                                               _Float16* __restrict__ C,
                                               int M, int N, int K) {
    __shared__ _Float16 smem[3 * 16384];
    const int t = threadIdx.x;
    const int w = t >> 6, l = t & 63;
    const int wr = w >> 1, wc = w & 1;
    const int NT = K >> 6;
    int row0 = blockIdx.y * 128, col0 = blockIdx.x * 128;

    f32x4 acc[4][4];
    #pragma unroll
    for (int m = 0; m < 4; ++m)
        #pragma unroll
        for (int n = 0; n < 4; ++n)
            acc[m][n] = (f32x4){0.f, 0.f, 0.f, 0.f};

    const int lr = l >> 3;
    const int lc8 = ((l & 7) ^ lr) * 8;

    auto STAGE = [&](int ti) {
        if (ti >= NT) return;
        int kk = ti << 6;
        int bufo = (ti % 3) * 16384;
        #pragma unroll
        for (int i = 0; i < 4; ++i) {
            int chunk = w * 4 + i;
            const _Float16* asrc = A + (size_t)(row0 + chunk * 8 + lr) * K + kk + lc8;
            __builtin_amdgcn_global_load_lds((const AS1 void*)asrc,
                (AS3 void*)(smem + bufo + chunk * 512), 16, 0, 0);
            const _Float16* bsrc = BT + (size_t)(col0 + chunk * 8 + lr) * K + kk + lc8;
            __builtin_amdgcn_global_load_lds((const AS1 void*)bsrc,
                (AS3 void*)(smem + bufo + 8192 + chunk * 512), 16, 0, 0);
        }
    };

    STAGE(0); STAGE(1);
    asm volatile("s_waitcnt vmcnt(8)" ::: "memory");
    __builtin_amdgcn_s_barrier();

    #pragma unroll 1
    for (int ti = 0; ti < NT; ++ti) {
        const int bufo = (ti % 3) * 16384;
        half8 a[4][2], bv[4][2];
        #pragma unroll
        for (int mf = 0; mf < 4; ++mf) {
            int r = wr * 64 + mf * 16 + (l & 15);
            #pragma unroll
            for (int ks = 0; ks < 2; ++ks) {
                int c16 = (ks * 4 + (l >> 4)) ^ (r & 7);
                a[mf][ks] = *(const half8*)&smem[bufo + r * 64 + c16 * 8];
            }
        }
        #pragma unroll
        for (int nf = 0; nf < 4; ++nf) {
            int r = wc * 64 + nf * 16 + (l & 15);
            #pragma unroll
            for (int ks = 0; ks < 2; ++ks) {
                int c16 = (ks * 4 + (l >> 4)) ^ (r & 7);
                bv[nf][ks] = *(const half8*)&smem[bufo + 8192 + r * 64 + c16 * 8];
            }
        }
        STAGE(ti + 2);
        __builtin_amdgcn_sched_barrier(0);
        asm volatile("s_waitcnt lgkmcnt(0)" ::: "memory");
        __builtin_amdgcn_sched_barrier(0);
        __builtin_amdgcn_s_setprio(1);
        #pragma unroll
        for (int mf = 0; mf < 4; ++mf)
            #pragma unroll
            for (int nf = 0; nf < 4; ++nf)
                #pragma unroll
                for (int ks = 0; ks < 2; ++ks)
                    acc[mf][nf] = __builtin_amdgcn_mfma_f32_16x16x32_f16(
                        a[mf][ks], bv[nf][ks], acc[mf][nf], 0, 0, 0);
        __builtin_amdgcn_s_setprio(0);
        __builtin_amdgcn_sched_barrier(0);
        if (ti < NT - 2) asm volatile("s_waitcnt vmcnt(8)" ::: "memory");
        else             asm volatile("s_waitcnt vmcnt(0)" ::: "memory");
        __builtin_amdgcn_s_barrier();
    }

    int ocol = l & 15, orow = (l >> 4) * 4;
    #pragma unroll
    for (int mf = 0; mf < 4; ++mf)
        #pragma unroll
        for (int nf = 0; nf < 4; ++nf) {
            size_t base = (size_t)(row0 + wr * 64 + mf * 16 + orow) * N
                        + col0 + wc * 64 + nf * 16 + ocol;
            #pragma unroll
            for (int j = 0; j < 4; ++j)
                C[base + (size_t)j * N] = (_Float16)acc[mf][nf][j];
        }
}

// ---------------------------------------------------------------------------
// kvagg_fused: per (bn, jseg): on-the-fly DPFP(k) + v, MFMA accumulate.
// jseg = 8 segments of 256 j's, grid (32, 8). f16 partials.
// ---------------------------------------------------------------------------
__global__ __launch_bounds__(512) void kvagg_fused(const _Float16* __restrict__ qkv,
                                                   _Float16* __restrict__ kvp,
                                                   float* __restrict__ zp) {
    __shared__ _Float16 x2s[128 * 64];    // 16 KB
    __shared__ _Float16 vTs[64 * 64];     //  8 KB
    __shared__ _Float16 pkTs[384 * 64];   // 48 KB
    const int t = threadIdx.x;
    const int w = t >> 6, l = t & 63;
    const int bn = blockIdx.x;
    const int jseg = blockIdx.y;    // 0..7 (256 j's each)
    const int b = bn >> 4, nh = bn & 15;

    f32x4 acc[4][3];
    #pragma unroll
    for (int mf = 0; mf < 4; ++mf)
        #pragma unroll
        for (int nf = 0; nf < 3; ++nf)
            acc[mf][nf] = (f32x4){0.f, 0.f, 0.f, 0.f};
    float zacc[3] = {0.f, 0.f, 0.f};

    const int sc = t & 63;
    const int so = t >> 6;

    #pragma unroll 1
    for (int ch = 0; ch < 4; ++ch) {
        int j0 = jseg * 256 + ch * 64;
        _Float16 kx[8], vx[8];
        #pragma unroll
        for (int e = 0; e < 8; ++e) {
            size_t rb = (size_t)((j0 + so * 8 + e) * 2 + b) * 3072 + nh * 64 + sc;
            kx[e] = qkv[rb + 1024];
            vx[e] = qkv[rb + 2048];
        }
        half8 xlo, xhi, vv;
        #pragma unroll
        for (int e = 0; e < 8; ++e) {
            float kf = (float)kx[e];
            xlo[e] = (_Float16)fmaxf(kf, 0.f);
            xhi[e] = (_Float16)fmaxf(-kf, 0.f);
            vv[e] = vx[e];
        }
        if (ch) __syncthreads();
        *(half8*)&x2s[IDX(sc, so)] = xlo;
        *(half8*)&x2s[IDX(sc + 64, so)] = xhi;
        *(half8*)&vTs[IDX(sc, so)] = vv;
        __syncthreads();
        {
            const int o = t & 7;
            const int fb = t >> 3;
            #pragma unroll
            for (int it = 0; it < 6; ++it) {
                int f = it * 64 + fb;
                int fm = f & 127;
                int r = (f >> 7) + 1;
                int fm2 = (fm - r) & 127;
                half8 pa = *(const half8*)&x2s[IDX(fm, o)];
                half8 pb = *(const half8*)&x2s[IDX(fm2, o)];
                *(half8*)&pkTs[IDX(f, o)] = pa * pb;
            }
        }
        __syncthreads();
        #pragma unroll
        for (int ks = 0; ks < 2; ++ks) {
            half8 a[4], bq[3];
            int oo = ks * 4 + (l >> 4);
            #pragma unroll
            for (int mf = 0; mf < 4; ++mf) {
                int dr = mf * 16 + (l & 15);
                a[mf] = *(const half8*)&vTs[IDX(dr, oo)];
            }
            #pragma unroll
            for (int nf = 0; nf < 3; ++nf) {
                int fr = w * 48 + nf * 16 + (l & 15);
                bq[nf] = *(const half8*)&pkTs[IDX(fr, oo)];
                #pragma unroll
                for (int e = 0; e < 8; ++e) zacc[nf] += (float)bq[nf][e];
            }
            #pragma unroll
            for (int mf = 0; mf < 4; ++mf)
                #pragma unroll
                for (int nf = 0; nf < 3; ++nf)
                    acc[mf][nf] = __builtin_amdgcn_mfma_f32_16x16x32_f16(
                        a[mf], bq[nf], acc[mf][nf], 0, 0, 0);
        }
    }

    #pragma unroll
    for (int nf = 0; nf < 3; ++nf) {
        float v = zacc[nf];
        v += __shfl_xor(v, 16, 64);
        v += __shfl_xor(v, 32, 64);
        if (l < 16)
            zp[(size_t)(jseg * 32 + bn) * FEAT + w * 48 + nf * 16 + l] = v;
    }
    _Float16* outp = kvp + (size_t)(jseg * 32 + bn) * 64 * FEAT;
    int orow = (l >> 4) * 4, ocol = l & 15;
    #pragma unroll
    for (int mf = 0; mf < 4; ++mf)
        #pragma unroll
        for (int nf = 0; nf < 3; ++nf) {
            int fcol = w * 48 + nf * 16 + ocol;
            #pragma unroll
            for (int j = 0; j < 4; ++j)
                outp[(size_t)(mf * 16 + orow + j) * FEAT + fcol] = (_Float16)acc[mf][nf][j];
        }
}

// ---------------------------------------------------------------------------
// Reduce 8 j-segments (f16 partials) -> kvaggT f16 [32][64][384], z f32
// ---------------------------------------------------------------------------
__global__ __launch_bounds__(256) void reduceA(const _Float16* __restrict__ kvp,
                                               const float* __restrict__ zp,
                                               _Float16* __restrict__ kvaggT,
                                               float* __restrict__ z) {
    const int NKV = 32 * 64 * FEAT;  // 786432
    int idx = blockIdx.x * 256 + threadIdx.x;
    if (idx < NKV) {
        float s = 0.f;
        #pragma unroll
        for (int c = 0; c < 8; ++c) s += (float)kvp[(size_t)c * NKV + idx];
        kvaggT[idx] = (_Float16)s;
    } else if (idx < NKV + 32 * FEAT) {
        int e = idx - NKV;
        float s = 0.f;
        #pragma unroll
        for (int c = 0; c < 8; ++c) s += zp[c * 32 * FEAT + e];
        z[e] = s;
    }
}

// ---------------------------------------------------------------------------
// attn_fused v2: 64 rows x 64 d per block, grid (32, 32), 256 threads.
// pq in registers via rotated-row trick. z reads vectorized.
// ---------------------------------------------------------------------------
#define X2STR 152   // 128 + 24 right-extension (max csel=24), halves
__global__ __launch_bounds__(256) void attn_fused(const _Float16* __restrict__ qkv,
                                                  const _Float16* __restrict__ kvaggT,
                                                  const float* __restrict__ z,
                                                  _Float16* __restrict__ av) {
    __shared__ _Float16 x2e[64 * X2STR];   // 19,456 B
    __shared__ _Float16 B_lds[64 * FEAT];  // 49,152 B, 16B-cell swizzle
    __shared__ float z_lds[FEAT];
    __shared__ float den_lds[64];
    const int t = threadIdx.x;
    const int w = t >> 6, l = t & 63;
    const int iblk = blockIdx.x;
    const int bn = blockIdx.y;
    const int b = bn >> 4, nh = bn & 15;

    {
        const _Float16* Bg = kvaggT + (size_t)bn * 64 * FEAT;
        #pragma unroll
        for (int s = 0; s < 12; ++s) {
            int idx8 = t + 256 * s;
            int row = idx8 / 48, c16 = idx8 - row * 48;
            half8 vv = *(const half8*)&Bg[row * FEAT + c16 * 8];
            *(half8*)&B_lds[row * FEAT + ((c16 ^ (row & 7)) << 3)] = vv;
        }
    }
    for (int e = t; e < FEAT; e += 256) z_lds[e] = z[(size_t)bn * FEAT + e];

    {
        int row = t >> 2, c0 = (t & 3) * 16;
        const _Float16* qrow = qkv + (size_t)((iblk * 64 + row) * 2 + b) * 3072 + nh * 64;
        half8 q0 = *(const half8*)&qrow[c0];
        half8 q1 = *(const half8*)&qrow[c0 + 8];
        half8 lo0, lo1, hi0, hi1;
        #pragma unroll
        for (int e = 0; e < 8; ++e) {
            float f0 = (float)q0[e], f1 = (float)q1[e];
            lo0[e] = (_Float16)fmaxf(f0, 0.f);
            lo1[e] = (_Float16)fmaxf(f1, 0.f);
            hi0[e] = (_Float16)fmaxf(-f0, 0.f);
            hi1[e] = (_Float16)fmaxf(-f1, 0.f);
        }
        _Float16* xr = &x2e[row * X2STR];
        *(half8*)&xr[c0] = lo0;
        *(half8*)&xr[c0 + 8] = lo1;
        *(half8*)&xr[64 + c0] = hi0;
        *(half8*)&xr[64 + c0 + 8] = hi1;
        if (c0 == 0) { *(half8*)&xr[128] = lo0; *(half8*)&xr[136] = lo1; }
        if (c0 == 16) { *(half8*)&xr[144] = lo0; }
    }
    __syncthreads();

    const int rloc16 = l & 15;
    const int csel = (l >> 4) * 8;
    const int lrow = w * 16 + rloc16;
    half8 y8[16];
    {
        const _Float16* xr = &x2e[lrow * X2STR + csel];
        #pragma unroll
        for (int j = 0; j < 16; ++j)
            y8[j] = *(const half8*)&xr[j * 8];
    }
    half8 afr[12];
    #pragma unroll
    for (int ks = 0; ks < 12; ++ks) {
        const int r = (ks >> 2) + 1;
        #pragma unroll
        for (int e = 0; e < 8; ++e) {
            const int j1 = ((ks & 3) * 32 + e) & 127;
            const int j2 = ((ks & 3) * 32 + e - r) & 127;
            afr[ks][e] = y8[j1 >> 3][j1 & 7] * y8[j2 >> 3][j2 & 7];
        }
    }

    f32x4 acc[4];
    #pragma unroll
    for (int n = 0; n < 4; ++n) acc[n] = (f32x4){0.f, 0.f, 0.f, 0.f};
    float den = 0.f;
    #pragma unroll
    for (int ks = 0; ks < 12; ++ks) {
        const float4 z0 = *(const float4*)&z_lds[ks * 32 + csel];
        const float4 z1 = *(const float4*)&z_lds[ks * 32 + csel + 4];
        den += (float)afr[ks][0] * z0.x + (float)afr[ks][1] * z0.y
             + (float)afr[ks][2] * z0.z + (float)afr[ks][3] * z0.w
             + (float)afr[ks][4] * z1.x + (float)afr[ks][5] * z1.y
             + (float)afr[ks][6] * z1.z + (float)afr[ks][7] * z1.w;
        #pragma unroll
        for (int nf = 0; nf < 4; ++nf) {
            int row = nf * 16 + rloc16;
            int c16 = (ks * 4 + (l >> 4)) ^ (row & 7);
            half8 bfr = *(const half8*)&B_lds[row * FEAT + (c16 << 3)];
            acc[nf] = __builtin_amdgcn_mfma_f32_16x16x32_f16(afr[ks], bfr, acc[nf], 0, 0, 0);
        }
    }

    den += __shfl_xor(den, 16, 64);
    den += __shfl_xor(den, 32, 64);
    if (l < 16) den_lds[w * 16 + l] = den;
    __syncthreads();

    #pragma unroll
    for (int nf = 0; nf < 4; ++nf)
        #pragma unroll
        for (int j = 0; j < 4; ++j) {
            int rl = w * 16 + (l >> 4) * 4 + j;
            float dv = den_lds[rl] * SCALE + EPS;
            float val = acc[nf][j] * SCALE / dv;
            int i = iblk * 64 + rl;
            av[((size_t)i * 2 + b) * 1024 + nh * 64 + nf * 16 + (l & 15)] = (_Float16)val;
        }
}

// ---------------------------------------------------------------------------
// Residual + LayerNorm, vectorized (float4 / half4).
// ---------------------------------------------------------------------------
__global__ __launch_bounds__(256) void ln_kernel(const float* __restrict__ h,
                                                 const _Float16* __restrict__ attn_out,
                                                 const float* __restrict__ gamma,
                                                 const float* __restrict__ beta,
                                                 float* __restrict__ out) {
    int r = blockIdx.x;
    int t = threadIdx.x;
    const float4 hv = ((const float4*)(h + (size_t)r * 1024))[t];
    const half4 a4 = ((const half4*)(attn_out + (size_t)r * 1024))[t];
    float x[4] = {hv.x + (float)a4[0], hv.y + (float)a4[1],
                  hv.z + (float)a4[2], hv.w + (float)a4[3]};
    float sum = x[0] + x[1] + x[2] + x[3];
    float sq = x[0]*x[0] + x[1]*x[1] + x[2]*x[2] + x[3]*x[3];
    #pragma unroll
    for (int off = 32; off >= 1; off >>= 1) {
        sum += __shfl_xor(sum, off, 64);
        sq += __shfl_xor(sq, off, 64);
    }
    __shared__ float ssum[4], ssq[4];
    int wl = t >> 6, lane = t & 63;
    if (lane == 0) { ssum[wl] = sum; ssq[wl] = sq; }
    __syncthreads();
    sum = ssum[0] + ssum[1] + ssum[2] + ssum[3];
    sq = ssq[0] + ssq[1] + ssq[2] + ssq[3];
    float mu = sum * (1.f / 1024.f);
    float var = sq * (1.f / 1024.f) - mu * mu;
    float rs = rsqrtf(var + 1e-5f);
    const float4 g4 = ((const float4*)gamma)[t];
    const float4 b4 = ((const float4*)beta)[t];
    float4 o;
    o.x = (x[0] - mu) * rs * g4.x + b4.x;
    o.y = (x[1] - mu) * rs * g4.y + b4.y;
    o.z = (x[2] - mu) * rs * g4.z + b4.z;
    o.w = (x[3] - mu) * rs * g4.w + b4.w;
    ((float4*)(out + (size_t)r * 1024))[t] = o;
}

// ---------------------------------------------------------------------------
extern "C" void kernel_launch(void* const* d_in, const int* in_sizes, int n_in,
                              void* d_out, int out_size, void* d_ws, size_t ws_size,
                              hipStream_t stream) {
    const float* h     = (const float*)d_in[0];
    const float* Wq    = (const float*)d_in[1];
    const float* Wkv   = (const float*)d_in[2];
    const float* Wo    = (const float*)d_in[3];
    const float* gamma = (const float*)d_in[4];
    const float* beta  = (const float*)d_in[5];
    float* out = (float*)d_out;
    _Float16* u = (_Float16*)d_ws;

    // Workspace (2-byte units)
    _Float16* h_h    = u;                       // 8 MB; later av (f16)
    _Float16* WqkvT  = u + 4194304;             // 6 MB
    _Float16* WoT    = u + 7340032;             // 2 MB
    _Float16* qkv    = u + 8388608;             // 24 MB; later attn_out f16
    _Float16* kvp    = u + 20971520;            // f16 partials, 8 segs = 12.6 MB
    float*    zp     = (float*)(u + 33554432);  // 8x32x384 f32
    _Float16* kvaggT = u + 33751040;            // 1.5 MB
    float*    z      = (float*)(u + 34537472);  // 48 KB
    _Float16* av         = h_h;
    _Float16* attn_out_h = qkv;

    dim3 blk(256);
    // 0) merged prep: conv h->f16 + weight transposes
    prep_kernel<<<dim3(8192), blk, 0, stream>>>(h, Wq, Wkv, Wo, h_h, WqkvT, WoT);
    // 1) fused qkv projection (single-barrier 256x192, best measured), grid 256
    gemm_qkv<<<dim3(256), dim3(512), 0, stream>>>(h_h, WqkvT, qkv, SB, 3072, DM);
    // 2) fused DPFP(k)+kvagg+z partials over (32 bn x 8 jseg)
    kvagg_fused<<<dim3(32, 8), dim3(512), 0, stream>>>(qkv, kvp, zp);
    // 3) reduce partials (8 segments)
    reduceA<<<dim3(3120), blk, 0, stream>>>(kvp, zp, kvaggT, z);
    // 4) fused featq + attn GEMM, pq-in-registers (grid 32 iblk x 32 bn)
    attn_fused<<<dim3(32, 32), blk, 0, stream>>>(qkv, kvaggT, z, av);
    // 5) output projection: 3-buffer counted-vmcnt kernel, grid (8, 32)
    gemm_wo<<<dim3(8, 32), blk, 0, stream>>>(av, WoT, attn_out_h, SB, 1024, DM);
    // 6) residual + LayerNorm
    ln_kernel<<<dim3(SB), blk, 0, stream>>>(h, attn_out_h, gamma, beta, out);
}